// Round 5
// baseline (302.937 us; speedup 1.0000x reference)
//
#include <hip/hip_runtime.h>
#include <hip/hip_bf16.h>
#include <stdint.h>

// Problem constants
constexpr int NA   = 10000;  // atoms
constexpr int NH   = 75;     // hidden
constexpr int NPF  = 14;     // pair features
constexpr int NW   = 5625;   // 75*75
constexpr int NCOL = 1200;   // 75*16: per h -> f=0..13 W-cols, f=14 bias, f=15 pad
constexpr int KP   = 104;    // K padded: 75 data, zeros to 96 (3 MFMA k-steps), 104 stride
constexpr int WIN  = 16;     // atoms (a1) per fused block; NA/WIN = 625 exactly
constexpr int USTR = 1208;   // U_lds row stride in ushorts (1200 + 8 pad; 604 dwords = 28 mod 32)

typedef _Float16 f16;
typedef __attribute__((ext_vector_type(2))) _Float16 f16x2;
typedef __attribute__((ext_vector_type(8))) _Float16 f16x8;
typedef __attribute__((ext_vector_type(4))) float floatx4;

__device__ __forceinline__ ushort f2h_bits(float f) {
    return __builtin_bit_cast(ushort, (f16)f);       // v_cvt_f16_f32, RNE
}
__device__ __forceinline__ f16x2 bch(uint32_t w) {
    return __builtin_bit_cast(f16x2, w);
}

// 16-wide f16 dot via 8x v_dot2_f32_f16 (f32 accumulate)
__device__ __forceinline__ float dot16(uint4 p0, uint4 p1, uint4 u0, uint4 u1, float c) {
    c = __builtin_amdgcn_fdot2(bch(p0.x), bch(u0.x), c, false);
    c = __builtin_amdgcn_fdot2(bch(p0.y), bch(u0.y), c, false);
    c = __builtin_amdgcn_fdot2(bch(p0.z), bch(u0.z), c, false);
    c = __builtin_amdgcn_fdot2(bch(p0.w), bch(u0.w), c, false);
    c = __builtin_amdgcn_fdot2(bch(p1.x), bch(u1.x), c, false);
    c = __builtin_amdgcn_fdot2(bch(p1.y), bch(u1.y), c, false);
    c = __builtin_amdgcn_fdot2(bch(p1.z), bch(u1.z), c, false);
    c = __builtin_amdgcn_fdot2(bch(p1.w), bch(u1.w), c, false);
    return c;
}

// ---------- K0: fused prep: cvt_af | cvt_w | cvt_pf | rowstart(a1) ----------
__global__ __launch_bounds__(256) void k_prep(
    const float* __restrict__ af, const float* __restrict__ W,
    const float* __restrict__ bias, const float* __restrict__ pf,
    const int* __restrict__ atp,
    ushort* __restrict__ afb, ushort* __restrict__ wbt,
    ushort* __restrict__ pfh, int* __restrict__ rs1,
    int E, int bA, int bW, int bP)
{
    const int b = blockIdx.x, tid = threadIdx.x;
    if (b < bA) {
        // af -> f16 [NA][KP], zero padded
        int idx = b * 256 + tid;
        if (idx >= NA * (KP / 4)) return;
        int a = idx / (KP / 4), q = idx - a * (KP / 4);
        int k0 = q * 4;
        ushort4 st = {0, 0, 0, 0};
        float v[4];
        #pragma unroll
        for (int j = 0; j < 4; ++j) {
            int k = k0 + j;
            v[j] = (k < NH) ? af[a * NH + k] : 0.f;
        }
        st.x = f2h_bits(v[0]); st.y = f2h_bits(v[1]);
        st.z = f2h_bits(v[2]); st.w = f2h_bits(v[3]);
        ((ushort4*)afb)[idx] = st;
    } else if (b < bA + bW) {
        // Wbt[c][k] f16, c = h*16+f (N-major)
        int idx = (b - bA) * 256 + tid;
        if (idx >= NCOL * (KP / 4)) return;
        int c = idx / (KP / 4), q = idx - c * (KP / 4);
        int k0 = q * 4;
        int h = c >> 4, f = c & 15;
        float v[4] = {0.f, 0.f, 0.f, 0.f};
        #pragma unroll
        for (int j = 0; j < 4; ++j) {
            int k = k0 + j;
            if (k < NH) {
                if (f < NPF)       v[j] = W[f * NW + h * NH + k];
                else if (f == NPF) v[j] = bias[h * NH + k];
            }
        }
        ushort4 st;
        st.x = f2h_bits(v[0]); st.y = f2h_bits(v[1]);
        st.z = f2h_bits(v[2]); st.w = f2h_bits(v[3]);
        ((ushort4*)wbt)[idx] = st;
    } else if (b < bA + bW + bP) {
        // pf -> f16x16 per edge, slot14 = 1.0 (bias), slot15 = 0
        int e = (b - bA - bW) * 256 + tid;
        if (e >= E) return;
        const float* pfe = pf + (size_t)e * NPF;
        union { f16 h[16]; uint4 q[2]; } u;
        #pragma unroll
        for (int f = 0; f < 7; ++f) {
            float2 t = *(const float2*)&pfe[2 * f];
            u.h[2 * f]     = (f16)t.x;
            u.h[2 * f + 1] = (f16)t.y;
        }
        u.h[14] = (f16)1.0f;
        u.h[15] = (f16)0.0f;
        uint4* dst = (uint4*)(pfh + (size_t)e * 16);
        dst[0] = u.q[0]; dst[1] = u.q[1];
    } else {
        // rowstart CSR on sorted atom_to_pair[:,1]
        int e = (b - bA - bW - bP) * 256 + tid;
        if (e >= E) return;
        int c  = atp[2 * e + 1];
        int cp = (e == 0) ? -1 : atp[2 * (e - 1) + 1];
        for (int a = cp + 1; a <= c; ++a) rs1[a] = e;
        if (e == E - 1)
            for (int a = c + 1; a <= NA; ++a) rs1[a] = E;
    }
}

// ---------- K1: fused per-a1-window GEMM (U in LDS) + edge scatter ----------
// Block b owns a1 in [16b, 16b+16). Phase 1: U_lds[16][1200] = afb_win @ Wbt^T
// via mfma(w_frag, a_frag) (wave w computes n-frags w,w+4,...). Phase 2: edges
// rs1[16b]..rs1[16b+16] (col-1-sorted -> contiguous), one edge/thread, 75
// h-dots from LDS, fp32 atomicAdd scatter to out (a0 ~ a1 -> L2-local).
__global__ __launch_bounds__(256) void k_fused(
    const ushort* __restrict__ afb, const ushort* __restrict__ wbt,
    const ushort* __restrict__ pfh, const int* __restrict__ atp,
    const int* __restrict__ rs1, float* __restrict__ out)
{
    __shared__ __align__(16) ushort U[WIN * USTR];   // 38656 B

    const int tid  = threadIdx.x;
    const int lane = tid & 63, wid = tid >> 6;
    const int ab0  = blockIdx.x * WIN;

    const int lr  = lane & 15;           // a-row within window / D col
    const int lko = (lane >> 4) * 8;     // k elem offset within 32-chunk

    // A-fragments for this window's 16 atoms (L2/HBM direct, 16B per lane)
    f16x8 a[3];
    #pragma unroll
    for (int ks = 0; ks < 3; ++ks)
        a[ks] = *(const f16x8*)&afb[(size_t)(ab0 + lr) * KP + ks * 32 + lko];

    // Phase 1: wave w computes n-frags nf = w, w+4, ... (cols nf*16..+15)
    for (int i = 0; i < 19; ++i) {
        int nf = wid + 4 * i;
        if (nf < 75) {
            floatx4 acc = {};
            #pragma unroll
            for (int ks = 0; ks < 3; ++ks) {
                f16x8 bfr = *(const f16x8*)&wbt[(size_t)(nf * 16 + lr) * KP + ks * 32 + lko];
                acc = __builtin_amdgcn_mfma_f32_16x16x32_f16(bfr, a[ks], acc, 0, 0, 0);
            }
            // D: col(lane&15)=a-row lr; reg-axis -> 4 consecutive c
            int cbase = nf * 16 + (lane >> 4) * 4;
            uint2 st;
            st.x = __builtin_bit_cast(uint32_t, __builtin_amdgcn_cvt_pkrtz(acc[0], acc[1]));
            st.y = __builtin_bit_cast(uint32_t, __builtin_amdgcn_cvt_pkrtz(acc[2], acc[3]));
            *(uint2*)&U[lr * USTR + cbase] = st;
        }
    }
    __syncthreads();

    // Phase 2: edge scatter
    const int e0 = rs1[ab0], e1 = rs1[ab0 + WIN];
    for (int e = e0 + tid; e < e1; e += 256) {
        int a0  = atp[2 * e];
        int la1 = atp[2 * e + 1] - ab0;
        const uint4* pq = (const uint4*)(pfh + (size_t)e * 16);
        uint4 p0 = pq[0], p1 = pq[1];
        const ushort* ur = U + la1 * USTR;
        float* orow = out + (size_t)a0 * NH;
        #pragma unroll 5
        for (int h = 0; h < NH; ++h) {
            const uint4* up = (const uint4*)(ur + h * 16);
            float s = dot16(p0, p1, up[0], up[1], 0.f);
            atomicAdd(&orow[h], s);
        }
    }
}

// ---------- Fallback: direct per-(edge,h) with atomics (fp32) ----------
__global__ void k_naive(const float* __restrict__ pf, const float* __restrict__ af,
                        const int* __restrict__ atp, const float* __restrict__ W,
                        const float* __restrict__ bias, float* __restrict__ out, int E)
{
    int idx = blockIdx.x * blockDim.x + threadIdx.x;
    if (idx >= E * NH) return;
    int e = idx / NH, h = idx - e * NH;
    int a0 = atp[2 * e], a1 = atp[2 * e + 1];
    float p[NPF];
    #pragma unroll
    for (int f = 0; f < NPF; ++f) p[f] = pf[(size_t)e * NPF + f];
    float acc = 0.f;
    for (int k = 0; k < NH; ++k) {
        float w = bias[h * NH + k];
        #pragma unroll
        for (int f = 0; f < NPF; ++f) w += p[f] * W[f * NW + h * NH + k];
        acc += w * af[a1 * NH + k];
    }
    atomicAdd(&out[a0 * NH + h], acc);
}

extern "C" void kernel_launch(void* const* d_in, const int* in_sizes, int n_in,
                              void* d_out, int out_size, void* d_ws, size_t ws_size,
                              hipStream_t stream) {
    const float* pf   = (const float*)d_in[0];
    const float* af   = (const float*)d_in[1];
    const int*   atp  = (const int*)d_in[2];
    const float* W    = (const float*)d_in[3];
    const float* bias = (const float*)d_in[4];
    float* out = (float*)d_out;
    const int E = in_sizes[2] / 2;

    const size_t offAfb = 0;
    const size_t offWbt = offAfb + (size_t)NA * KP * 2;        // 2,080,000
    const size_t offPfh = offWbt + (size_t)NCOL * KP * 2;      // +249,600
    const size_t offRs  = offPfh + (size_t)E * 16 * 2;         // +2,048,000
    const size_t need   = offRs + (size_t)(NA + 1) * sizeof(int);

    if (ws_size >= need) {
        ushort* afb = (ushort*)((char*)d_ws + offAfb);
        ushort* wbt = (ushort*)((char*)d_ws + offWbt);
        ushort* pfh = (ushort*)((char*)d_ws + offPfh);
        int*    rs1 = (int*)((char*)d_ws + offRs);

        hipMemsetAsync(d_out, 0, (size_t)out_size * sizeof(float), stream);

        const int bA = (NA * (KP / 4) + 255) / 256;     // 1016
        const int bW = (NCOL * (KP / 4) + 255) / 256;   // 122
        const int bP = (E + 255) / 256;                 // 250
        const int bR = (E + 255) / 256;                 // 250
        k_prep<<<bA + bW + bP + bR, 256, 0, stream>>>(af, W, bias, pf, atp,
                                                      afb, wbt, pfh, rs1, E, bA, bW, bP);

        k_fused<<<NA / WIN, 256, 0, stream>>>(afb, wbt, pfh, atp, rs1, out);
    } else {
        hipMemsetAsync(d_out, 0, (size_t)out_size * sizeof(float), stream);
        k_naive<<<((size_t)E * NH + 255) / 256, 256, 0, stream>>>(pf, af, atp, W, bias, out, E);
    }
}

// Round 6
// 34.792 us; speedup vs baseline: 8.7071x; 8.7071x over previous
//
#include <hip/hip_runtime.h>
#include <hip/hip_bf16.h>
#include <stdint.h>

// Problem constants
constexpr int NA   = 10000;  // atoms
constexpr int NH   = 75;     // hidden
constexpr int NPF  = 14;     // pair features
constexpr int NW   = 5625;   // 75*75
constexpr int NCOL = 1200;   // 75*16: per h -> f=0..13 W-cols, f=14 bias, f=15 pad
constexpr int KP   = 104;    // K padded: 75 data, zeros to 96 (3 MFMA k-steps), 104 stride
constexpr int MROW = 10112;  // NA padded to 79*128
constexpr int WROW = 1208;   // NCOL padded rows for staging slack
constexpr int JSL  = 38;     // h-slots per atom in k_edges (thread does h=j and h=j+38)
constexpr int BN   = 240;    // gemm col-tile (15 n-frags), NCOL/BN = 5
constexpr int ACH  = 26;     // A staging chunks of 1024B (128*104*2 = 26624B)
constexpr int BCH  = 49;     // B staging chunks (240*104*2 = 49920B -> 49 w/ slack)

typedef _Float16 f16;
typedef __attribute__((ext_vector_type(2))) _Float16 f16x2;
typedef __attribute__((ext_vector_type(8))) _Float16 f16x8;
typedef __attribute__((ext_vector_type(4))) float floatx4;

__device__ __forceinline__ ushort f2h_bits(float f) {
    return __builtin_bit_cast(ushort, (f16)f);       // v_cvt_f16_f32, RNE
}
__device__ __forceinline__ f16x2 bch(uint32_t w) {
    return __builtin_bit_cast(f16x2, w);
}

__device__ __forceinline__ void gload16(const void* g, void* l) {
    __builtin_amdgcn_global_load_lds(
        (const __attribute__((address_space(1))) uint32_t*)g,
        (__attribute__((address_space(3))) uint32_t*)l, 16, 0, 0);
}

// bijective XCD chunk swizzle (m204): contiguous work chunk per XCD
__device__ __forceinline__ int xcd_swz(int orig, int nwg) {
    int q = nwg >> 3, r = nwg & 7;
    int xcd = orig & 7, i = orig >> 3;
    return (xcd < r ? xcd * (q + 1) : r * (q + 1) + (xcd - r) * q) + i;
}

// 16-wide f16 dot via 8x v_dot2_f32_f16 (f32 accumulate)
__device__ __forceinline__ float dot16(uint4 p0, uint4 p1, uint4 u0, uint4 u1, float c) {
    c = __builtin_amdgcn_fdot2(bch(p0.x), bch(u0.x), c, false);
    c = __builtin_amdgcn_fdot2(bch(p0.y), bch(u0.y), c, false);
    c = __builtin_amdgcn_fdot2(bch(p0.z), bch(u0.z), c, false);
    c = __builtin_amdgcn_fdot2(bch(p0.w), bch(u0.w), c, false);
    c = __builtin_amdgcn_fdot2(bch(p1.x), bch(u1.x), c, false);
    c = __builtin_amdgcn_fdot2(bch(p1.y), bch(u1.y), c, false);
    c = __builtin_amdgcn_fdot2(bch(p1.z), bch(u1.z), c, false);
    c = __builtin_amdgcn_fdot2(bch(p1.w), bch(u1.w), c, false);
    return c;
}

// ---------- K0: fused prep: cvt_af | cvt_w | cvt_pf | rowstart(a0) ----------
__global__ __launch_bounds__(256) void k_prep(
    const float* __restrict__ af, const float* __restrict__ W,
    const float* __restrict__ bias, const float* __restrict__ pf,
    const int* __restrict__ atp,
    ushort* __restrict__ afb, ushort* __restrict__ wbt,
    ushort* __restrict__ pfh, int* __restrict__ rs,
    int E, int bA, int bW, int bP)
{
    const int b = blockIdx.x, tid = threadIdx.x;
    if (b < bA) {
        // af -> f16 [MROW][KP], zero padded
        int idx = b * 256 + tid;
        if (idx >= MROW * (KP / 4)) return;
        int a = idx / (KP / 4), q = idx - a * (KP / 4);
        int k0 = q * 4;
        ushort4 st = {0, 0, 0, 0};
        if (a < NA) {
            float v[4];
            #pragma unroll
            for (int j = 0; j < 4; ++j) {
                int k = k0 + j;
                v[j] = (k < NH) ? af[a * NH + k] : 0.f;
            }
            st.x = f2h_bits(v[0]); st.y = f2h_bits(v[1]);
            st.z = f2h_bits(v[2]); st.w = f2h_bits(v[3]);
        }
        ((ushort4*)afb)[idx] = st;
    } else if (b < bA + bW) {
        // Wbt[c][k] f16, c = h*16+f (N-major)
        int idx = (b - bA) * 256 + tid;
        if (idx >= WROW * (KP / 4)) return;
        int c = idx / (KP / 4), q = idx - c * (KP / 4);
        int k0 = q * 4;
        ushort4 st = {0, 0, 0, 0};
        if (c < NCOL) {
            int h = c >> 4, f = c & 15;
            float v[4] = {0.f, 0.f, 0.f, 0.f};
            #pragma unroll
            for (int j = 0; j < 4; ++j) {
                int k = k0 + j;
                if (k < NH) {
                    if (f < NPF)       v[j] = W[f * NW + h * NH + k];
                    else if (f == NPF) v[j] = bias[h * NH + k];
                }
            }
            st.x = f2h_bits(v[0]); st.y = f2h_bits(v[1]);
            st.z = f2h_bits(v[2]); st.w = f2h_bits(v[3]);
        }
        ((ushort4*)wbt)[idx] = st;
    } else if (b < bA + bW + bP) {
        // pf -> f16x16 per edge, slot14 = 1.0 (bias), slot15 = 0
        int e = (b - bA - bW) * 256 + tid;
        if (e >= E) return;
        const float* pfe = pf + (size_t)e * NPF;
        union { f16 h[16]; uint4 q[2]; } u;
        #pragma unroll
        for (int f = 0; f < 7; ++f) {
            float2 t = *(const float2*)&pfe[2 * f];
            u.h[2 * f]     = (f16)t.x;
            u.h[2 * f + 1] = (f16)t.y;
        }
        u.h[14] = (f16)1.0f;
        u.h[15] = (f16)0.0f;
        uint4* dst = (uint4*)(pfh + (size_t)e * 16);
        dst[0] = u.q[0]; dst[1] = u.q[1];
    } else {
        // rowstart CSR from sorted atom_to_pair[:,0]
        int e = (b - bA - bW - bP) * 256 + tid;
        if (e >= E) return;
        int c  = atp[2 * e];
        int cp = (e == 0) ? -1 : atp[2 * (e - 1)];
        for (int a = cp + 1; a <= c; ++a) rs[a] = e;
        if (e == E - 1)
            for (int a = c + 1; a <= NA; ++a) rs[a] = E;
    }
}

// ---------- K1: MFMA GEMM  U[a][c] = sum_k afb[a][k]*Wbt[c][k], U stored f16 ----------
// Tile 128x240, 4 waves. 1D grid, y-major flatten (5 consecutive blocks share an
// A-panel) + XCD chunk swizzle -> per-XCD L2 locality for afb; wbt (250KB) is
// L2-resident on every XCD.
__global__ __launch_bounds__(256, 2) void k_gemm(const ushort* __restrict__ afb,
                                                 const ushort* __restrict__ wbt,
                                                 ushort* __restrict__ U) {
    __shared__ __align__(16) ushort sm[38400];         // 26624B A + 50176B B
    ushort* As = sm;                                   // [128][104]
    ushort* Bs = sm + 13312;                           // [~241][104]

    const int nwg = (NCOL / BN) * (MROW / 128);        // 395
    const int swz = xcd_swz(blockIdx.x, nwg);
    const int by  = swz / (NCOL / BN);
    const int bx  = swz - by * (NCOL / BN);

    const int tid  = threadIdx.x;
    const int lane = tid & 63, wid = tid >> 6;
    const int a0 = by * 128;
    const int c0 = bx * BN;

    const char* aSrc = (const char*)(afb + (size_t)a0 * KP);
    const char* bSrc = (const char*)(wbt + (size_t)c0 * KP);

    for (int c = wid; c < ACH + BCH; c += 4) {
        if (c < ACH) gload16(aSrc + c * 1024 + lane * 16, (char*)As + c * 1024);
        else {
            int cb = c - ACH;
            gload16(bSrc + cb * 1024 + lane * 16, (char*)Bs + cb * 1024);
        }
    }
    __syncthreads();

    const int lr = lane & 15;          // frag row; D col
    const int lk = (lane >> 4) * 8;    // frag k-base
    floatx4 acc[15][2] = {};

    #pragma unroll
    for (int ks = 0; ks < 3; ++ks) {
        f16x8 a[2], bv[15];
        #pragma unroll
        for (int mf = 0; mf < 2; ++mf)
            a[mf] = *(const f16x8*)&As[(wid * 32 + mf * 16 + lr) * KP + ks * 32 + lk];
        #pragma unroll
        for (int nf = 0; nf < 15; ++nf)
            bv[nf] = *(const f16x8*)&Bs[(nf * 16 + lr) * KP + ks * 32 + lk];
        #pragma unroll
        for (int nf = 0; nf < 15; ++nf)
            #pragma unroll
            for (int mf = 0; mf < 2; ++mf)
                acc[nf][mf] = __builtin_amdgcn_mfma_f32_16x16x32_f16(
                    bv[nf], a[mf], acc[nf][mf], 0, 0, 0);
    }

    // D: col=lane&15 -> a-row; reg-axis -> 4 consecutive c
    #pragma unroll
    for (int mf = 0; mf < 2; ++mf) {
        int arow = a0 + wid * 32 + mf * 16 + lr;
        if (arow >= NA) continue;
        #pragma unroll
        for (int nf = 0; nf < 15; ++nf) {
            int cbase = c0 + nf * 16 + (lane >> 4) * 4;
            uint2 st;
            st.x = __builtin_bit_cast(uint32_t,
                     __builtin_amdgcn_cvt_pkrtz(acc[nf][mf][0], acc[nf][mf][1]));
            st.y = __builtin_bit_cast(uint32_t,
                     __builtin_amdgcn_cvt_pkrtz(acc[nf][mf][2], acc[nf][mf][3]));
            *(uint2*)&U[(size_t)arow * NCOL + cbase] = st;
        }
    }
}

// ---------- K2: per-(atom, j) edge loop; thread handles h=j and h=j+38 ----------
// XCD chunk swizzle: each XCD owns a contiguous ~1250-atom range, whose U band
// (~3 MB) and pfh band (~256 KB) fit its 4 MiB L2 (both index cols are sorted).
__global__ __launch_bounds__(256) void k_edges2(
    const ushort* __restrict__ pfh, const int* __restrict__ atp,
    const int* __restrict__ rs, const ushort* __restrict__ U,
    float* __restrict__ out, int nwg)
{
    int blk = xcd_swz(blockIdx.x, nwg);
    int idx = blk * 256 + threadIdx.x;
    if (idx >= NA * JSL) return;
    int a = idx / JSL;
    int j = idx - a * JSL;
    const bool two = (j + JSL) < NH;   // j < 37
    int e0 = rs[a], e1 = rs[a + 1];

    float acc0 = 0.f, acc1 = 0.f;
    for (int e = e0; e < e1; ++e) {
        int a1 = atp[2 * e + 1];
        const uint4* pq = (const uint4*)(pfh + (size_t)e * 16);
        uint4 p0 = pq[0], p1 = pq[1];
        const ushort* ub = U + (size_t)a1 * NCOL;
        {
            const uint4* up = (const uint4*)(ub + j * 16);
            acc0 = dot16(p0, p1, up[0], up[1], acc0);
        }
        if (two) {
            const uint4* up = (const uint4*)(ub + (j + JSL) * 16);
            acc1 = dot16(p0, p1, up[0], up[1], acc1);
        }
    }
    out[a * NH + j] = acc0;
    if (two) out[a * NH + j + JSL] = acc1;
}

// ---------- Fallback: direct per-(edge,h) with atomics (fp32) ----------
__global__ void k_naive(const float* __restrict__ pf, const float* __restrict__ af,
                        const int* __restrict__ atp, const float* __restrict__ W,
                        const float* __restrict__ bias, float* __restrict__ out, int E)
{
    int idx = blockIdx.x * blockDim.x + threadIdx.x;
    if (idx >= E * NH) return;
    int e = idx / NH, h = idx - e * NH;
    int a0 = atp[2 * e], a1 = atp[2 * e + 1];
    float p[NPF];
    #pragma unroll
    for (int f = 0; f < NPF; ++f) p[f] = pf[(size_t)e * NPF + f];
    float acc = 0.f;
    for (int k = 0; k < NH; ++k) {
        float w = bias[h * NH + k];
        #pragma unroll
        for (int f = 0; f < NPF; ++f) w += p[f] * W[f * NW + h * NH + k];
        acc += w * af[a1 * NH + k];
    }
    atomicAdd(&out[a0 * NH + h], acc);
}

extern "C" void kernel_launch(void* const* d_in, const int* in_sizes, int n_in,
                              void* d_out, int out_size, void* d_ws, size_t ws_size,
                              hipStream_t stream) {
    const float* pf   = (const float*)d_in[0];
    const float* af   = (const float*)d_in[1];
    const int*   atp  = (const int*)d_in[2];
    const float* W    = (const float*)d_in[3];
    const float* bias = (const float*)d_in[4];
    float* out = (float*)d_out;
    const int E = in_sizes[2] / 2;

    const size_t offAfb = 0;
    const size_t offWbt = offAfb + (size_t)MROW * KP * 2;
    const size_t offU   = offWbt + (size_t)WROW * KP * 2;
    const size_t offPfh = offU + (size_t)NA * NCOL * 2;
    const size_t offRs  = offPfh + (size_t)E * 16 * 2;
    const size_t need   = offRs + (size_t)(NA + 1) * sizeof(int);

    if (ws_size >= need) {
        ushort* afb = (ushort*)((char*)d_ws + offAfb);
        ushort* wbt = (ushort*)((char*)d_ws + offWbt);
        ushort* U   = (ushort*)((char*)d_ws + offU);
        ushort* pfh = (ushort*)((char*)d_ws + offPfh);
        int*    rs  = (int*)((char*)d_ws + offRs);

        const int bA = (MROW * (KP / 4) + 255) / 256;   // 1027
        const int bW = (WROW * (KP / 4) + 255) / 256;   // 123
        const int bP = (E + 255) / 256;                 // 250
        const int bR = (E + 255) / 256;                 // 250
        k_prep<<<bA + bW + bP + bR, 256, 0, stream>>>(af, W, bias, pf, atp,
                                                      afb, wbt, pfh, rs, E, bA, bW, bP);

        k_gemm<<<(NCOL / BN) * (MROW / 128), 256, 0, stream>>>(afb, wbt, U);

        const int nwg2 = (NA * JSL + 255) / 256;        // 1485
        k_edges2<<<nwg2, 256, 0, stream>>>(pfh, atp, rs, U, out, nwg2);
    } else {
        hipMemsetAsync(d_out, 0, (size_t)out_size * sizeof(float), stream);
        k_naive<<<((size_t)E * NH + 255) / 256, 256, 0, stream>>>(pf, af, atp, W, bias, out, E);
    }
}